// Round 16
// baseline (208.316 us; speedup 1.0000x reference)
//
#include <hip/hip_runtime.h>
#include <type_traits>

#define NN 100000
#define FB_SH 10                 // fine bucket shift: bucket = col >> 10
#define FB_N  1024               // nodes per bucket
#define NFB   98                 // ceil(100000/1024)
#define NBLK  256                // binning blocks
#define BH_TOT (NFB * NBLK)      // 25088

// bf16 helpers (RN-even)
static __device__ __forceinline__ unsigned short f2bf(float f) {
    unsigned u = __float_as_uint(f);
    u += 0x7fffu + ((u >> 16) & 1u);
    return (unsigned short)(u >> 16);
}
static __device__ __forceinline__ float bf2f(unsigned short h) {
    return __uint_as_float(((unsigned)h) << 16);
}

// ================= CSR build: stable two-pass counting sort =================
// chunk is a multiple of 4 (host guarantees) so int4 loads are aligned.

__global__ __launch_bounds__(256) void k_hist1(const int* __restrict__ coli,
                                               int* __restrict__ bhist, int E, int chunk) {
    __shared__ int h[NFB];
    for (int i = threadIdx.x; i < NFB; i += 256) h[i] = 0;
    __syncthreads();
    int bk = blockIdx.x;
    int beg = bk * chunk, end = min(E, beg + chunk);
    for (int e = beg + threadIdx.x * 4; e < end; e += 1024) {
        if (e + 4 <= end) {
            int4 c = *(const int4*)&coli[e];
            atomicAdd(&h[c.x >> FB_SH], 1);
            atomicAdd(&h[c.y >> FB_SH], 1);
            atomicAdd(&h[c.z >> FB_SH], 1);
            atomicAdd(&h[c.w >> FB_SH], 1);
        } else {
            for (int t = e; t < end; ++t) atomicAdd(&h[coli[t] >> FB_SH], 1);
        }
    }
    __syncthreads();
    for (int i = threadIdx.x; i < NFB; i += 256)
        bhist[i * NBLK + bk] = h[i];   // bucket-major for the scan
}

__global__ __launch_bounds__(1024) void k_scanA(int* __restrict__ a,
                                                int* __restrict__ blksum, int n) {
    __shared__ int sh[1024];
    int i = blockIdx.x * 1024 + threadIdx.x;
    int v = (i < n) ? a[i] : 0;
    sh[threadIdx.x] = v;
    __syncthreads();
    #pragma unroll
    for (int d = 1; d < 1024; d <<= 1) {
        int t = (threadIdx.x >= d) ? sh[threadIdx.x - d] : 0;
        __syncthreads();
        sh[threadIdx.x] += t;
        __syncthreads();
    }
    if (i < n) a[i] = sh[threadIdx.x] - v;   // local exclusive
    if (threadIdx.x == 1023) blksum[blockIdx.x] = sh[1023];
}

// scanB fused in: each block loads the raw block sums, thread 0 scans in LDS.
__global__ __launch_bounds__(256) void k_scanC(int* __restrict__ a,
                                               const int* __restrict__ blksum,
                                               int nbs, int n,
                                               int* __restrict__ off, int E) {
    __shared__ int pre[32];
    if (threadIdx.x < 32) pre[threadIdx.x] = (threadIdx.x < nbs) ? blksum[threadIdx.x] : 0;
    __syncthreads();
    if (threadIdx.x == 0) {
        int s = 0;
        for (int b = 0; b < nbs; ++b) { int t = pre[b]; pre[b] = s; s += t; }
    }
    __syncthreads();
    int i = blockIdx.x * 256 + threadIdx.x;
    if (i < n) a[i] += pre[i >> 10];
    if (i == 0) off[NN] = E;
}

__global__ __launch_bounds__(256) void k_bin2(
    const int* __restrict__ rowi, const int* __restrict__ coli,
    const int* __restrict__ bbase, unsigned int* __restrict__ cbin, int E, int chunk)
{
    __shared__ int cur[NFB];
    int bk = blockIdx.x;
    for (int i = threadIdx.x; i < NFB; i += 256) cur[i] = bbase[i * NBLK + bk];
    __syncthreads();
    int beg = bk * chunk, end = min(E, beg + chunk);
    for (int e = beg + threadIdx.x * 4; e < end; e += 1024) {
        if (e + 4 <= end) {
            int4 c = *(const int4*)&coli[e];
            int4 r = *(const int4*)&rowi[e];
            int b0 = c.x >> FB_SH, b1 = c.y >> FB_SH, b2 = c.z >> FB_SH, b3 = c.w >> FB_SH;
            unsigned v0 = ((unsigned)r.x << FB_SH) | (unsigned)(c.x & (FB_N - 1));
            unsigned v1 = ((unsigned)r.y << FB_SH) | (unsigned)(c.y & (FB_N - 1));
            unsigned v2 = ((unsigned)r.z << FB_SH) | (unsigned)(c.z & (FB_N - 1));
            unsigned v3 = ((unsigned)r.w << FB_SH) | (unsigned)(c.w & (FB_N - 1));
            cbin[atomicAdd(&cur[b0], 1)] = v0;
            cbin[atomicAdd(&cur[b1], 1)] = v1;
            cbin[atomicAdd(&cur[b2], 1)] = v2;
            cbin[atomicAdd(&cur[b3], 1)] = v3;
        } else {
            for (int t = e; t < end; ++t) {
                int col = coli[t], row = rowi[t];
                int b = col >> FB_SH;
                unsigned val = ((unsigned)row << FB_SH) | (unsigned)(col & (FB_N - 1));
                cbin[atomicAdd(&cur[b], 1)] = val;
            }
        }
    }
}

__global__ __launch_bounds__(1024) void k_csr(
    const unsigned int* __restrict__ cbin, const int* __restrict__ bbase,
    int* __restrict__ off, float* __restrict__ dinv,
    int* __restrict__ srcs, int n, int E)
{
    __shared__ int hist[FB_N];
    __shared__ int wsum[16];
    int b = blockIdx.x;
    int beg = bbase[b * NBLK];
    int end = (b + 1 < NFB) ? bbase[(b + 1) * NBLK] : E;
    int tid = threadIdx.x;
    hist[tid] = 0;
    __syncthreads();
    // aligned sub-range for uint4 loads
    int beg4 = min((beg + 3) & ~3, end);
    int end4 = max(end & ~3, beg4);
    int nhead = beg4 - beg;          // 0..3
    int ntail = end - end4;          // 0..3
    // pass A: per-node histogram
    if (tid < nhead) atomicAdd(&hist[cbin[beg + tid] & (FB_N - 1)], 1);
    if (tid >= 4 && tid < 4 + ntail) atomicAdd(&hist[cbin[end4 + tid - 4] & (FB_N - 1)], 1);
    for (int e = beg4 + tid * 4; e < end4; e += 4096) {
        uint4 c = *(const uint4*)&cbin[e];
        atomicAdd(&hist[c.x & (FB_N - 1)], 1);
        atomicAdd(&hist[c.y & (FB_N - 1)], 1);
        atomicAdd(&hist[c.z & (FB_N - 1)], 1);
        atomicAdd(&hist[c.w & (FB_N - 1)], 1);
    }
    __syncthreads();
    int v = hist[tid];
    int lane = tid & 63;
    int wid  = tid >> 6;
    int incl = v;
    #pragma unroll
    for (int d = 1; d < 64; d <<= 1) {
        int t = __shfl_up(incl, d, 64);
        if (lane >= d) incl += t;
    }
    if (lane == 63) wsum[wid] = incl;
    __syncthreads();
    if (wid == 0) {
        int ws = (lane < 16) ? wsum[lane] : 0;
        int wincl = ws;
        #pragma unroll
        for (int d = 1; d < 16; d <<= 1) {
            int t = __shfl_up(wincl, d, 64);
            if (lane >= d) wincl += t;
        }
        if (lane < 16) wsum[lane] = wincl - ws;
    }
    __syncthreads();
    int excl = wsum[wid] + incl - v;
    int node = (b << FB_SH) + tid;
    if (node < n) {
        off[node]  = beg + excl;
        dinv[node] = rsqrtf((float)(v + 1));   // +1 self-loop
    }
    __syncthreads();
    hist[tid] = excl;   // becomes cursor
    __syncthreads();
    // pass B: place rows
    if (tid < nhead) {
        unsigned pv = cbin[beg + tid];
        srcs[beg + atomicAdd(&hist[pv & (FB_N - 1)], 1)] = (int)(pv >> FB_SH);
    }
    if (tid >= 4 && tid < 4 + ntail) {
        unsigned pv = cbin[end4 + tid - 4];
        srcs[beg + atomicAdd(&hist[pv & (FB_N - 1)], 1)] = (int)(pv >> FB_SH);
    }
    for (int e = beg4 + tid * 4; e < end4; e += 4096) {
        uint4 c = *(const uint4*)&cbin[e];
        srcs[beg + atomicAdd(&hist[c.x & (FB_N - 1)], 1)] = (int)(c.x >> FB_SH);
        srcs[beg + atomicAdd(&hist[c.y & (FB_N - 1)], 1)] = (int)(c.y >> FB_SH);
        srcs[beg + atomicAdd(&hist[c.z & (FB_N - 1)], 1)] = (int)(c.z >> FB_SH);
        srcs[beg + atomicAdd(&hist[c.w & (FB_N - 1)], 1)] = (int)(c.w >> FB_SH);
    }
}

// ================= GEMM (layer 1): Ybf1 = bf16((X @ W1) * dinv[row]) =================
__global__ __launch_bounds__(256) void k_gemm64(
    const float* __restrict__ X, const float* __restrict__ W,
    const float* __restrict__ dinv, unsigned short* __restrict__ Ybf, int n)
{
    constexpr int DOUT = 64;
    constexpr int TPR = DOUT / 4;    // 16
    constexpr int R   = 256 / TPR;   // 16
    __shared__ float sW[64 * DOUT];
    __shared__ float sX[R * 64];

    for (int i = threadIdx.x; i < 16 * DOUT; i += 256)
        *(float4*)&sW[i * 4] = *(const float4*)&W[i * 4];
    int r0 = blockIdx.x * R;
    for (int i = threadIdx.x; i < R * 16; i += 256) {
        int lr  = i >> 4;
        int c4i = (i & 15) * 4;
        int r = r0 + lr;
        float4 v = (r < n) ? *(const float4*)&X[(size_t)r * 64 + c4i]
                           : make_float4(0.f, 0.f, 0.f, 0.f);
        *(float4*)&sX[lr * 64 + c4i] = v;
    }
    __syncthreads();

    int lr  = threadIdx.x / TPR;
    int c4  = (threadIdx.x % TPR) * 4;
    int row = r0 + lr;
    const float* xr = &sX[lr * 64];
    float4 acc = make_float4(0.f, 0.f, 0.f, 0.f);
    #pragma unroll
    for (int k = 0; k < 64; ++k) {
        float xv = xr[k];
        const float* wr = &sW[k * DOUT + c4];
        acc.x = fmaf(xv, wr[0], acc.x);
        acc.y = fmaf(xv, wr[1], acc.y);
        acc.z = fmaf(xv, wr[2], acc.z);
        acc.w = fmaf(xv, wr[3], acc.w);
    }
    if (row < n) {
        float s = dinv[row];
        ushort4 o;
        o.x = f2bf(acc.x * s);
        o.y = f2bf(acc.y * s);
        o.z = f2bf(acc.z * s);
        o.w = f2bf(acc.w * s);
        *(ushort4*)&Ybf[(size_t)row * DOUT + c4] = o;
    }
}

// ======== FUSED layer-1 aggregate + layer-2 GEMM (persistent grid-stride) ========
// Per node (one wave): h = relu(dinv*(Y1[i]+sum Y1[src]) + b1), then
// Ybf2[node] = bf16(dinv[node] * (h @ W2)).
// W2 column lives in registers (32 VGPR, const-indexed full unroll);
// h staged per-wave in LDS (same-wave dep, no barrier).
#define AGG_BLKS 2048
__global__ __launch_bounds__(256) void k_agg64g(
    const unsigned short* __restrict__ Ybf, const int* __restrict__ off,
    const int* __restrict__ srcs, const float* __restrict__ dinv,
    const float* __restrict__ bias, const float* __restrict__ W2,
    unsigned short* __restrict__ Y2, int n)
{
    __shared__ float sH[4][64];
    int w  = threadIdx.x >> 6;
    int l  = threadIdx.x & 63;
    int h  = l >> 5;             // edge slot / k-half (0/1)
    int ch = (l & 31) * 2;       // channel pair
    int jc = l & 31;             // output column for the matvec

    // W2 column in registers: wreg[k] = W2[h*32+k][jc] (coalesced, L2-hot)
    float wreg[32];
    #pragma unroll
    for (int k = 0; k < 32; ++k)
        wreg[k] = W2[(h * 32 + k) * 32 + jc];
    float b0 = bias[ch], b1 = bias[ch + 1];

    for (int node = blockIdx.x * 4 + w; node < n; node += AGG_BLKS * 4) {
        int beg = off[node], end = off[node + 1];
        float a0 = 0.f, a1 = 0.f;
        int j = beg;
        for (; j + 16 <= end; j += 16) {
            #pragma unroll
            for (int k = 0; k < 8; ++k) {
                int src = srcs[j + 2 * k + h];
                ushort2 u = *(const ushort2*)&Ybf[(size_t)src * 64 + ch];
                a0 += bf2f(u.x); a1 += bf2f(u.y);
            }
        }
        for (; j + 2 <= end; j += 2) {
            int src = srcs[j + h];
            ushort2 u = *(const ushort2*)&Ybf[(size_t)src * 64 + ch];
            a0 += bf2f(u.x); a1 += bf2f(u.y);
        }
        if (h == 0) {
            if (j < end) {   // odd leftover edge
                int src = srcs[j];
                ushort2 u = *(const ushort2*)&Ybf[(size_t)src * 64 + ch];
                a0 += bf2f(u.x); a1 += bf2f(u.y);
            }
            // self-loop
            ushort2 u = *(const ushort2*)&Ybf[(size_t)node * 64 + ch];
            a0 += bf2f(u.x); a1 += bf2f(u.y);
        }
        a0 += __shfl_xor(a0, 32, 64);
        a1 += __shfl_xor(a1, 32, 64);
        float d = dinv[node];
        if (h == 0) {
            sH[w][ch]     = fmaxf(fmaf(d, a0, b0), 0.f);
            sH[w][ch + 1] = fmaxf(fmaf(d, a1, b1), 0.f);
        }
        // matvec: 32 broadcast LDS reads + 32 FMA (same-wave LDS dep)
        const float* hrow = &sH[w][h * 32];
        float acc2 = 0.f;
        #pragma unroll
        for (int k = 0; k < 32; ++k)
            acc2 = fmaf(hrow[k], wreg[k], acc2);
        acc2 += __shfl_xor(acc2, 32, 64);
        if (h == 0)
            Y2[(size_t)node * 32 + jc] = f2bf(d * acc2);
    }
}

// D=32: one 64-lane wave per node; lane = (edge slot q 0..3, channel pair ch).
__global__ __launch_bounds__(256) void k_agg32(
    const unsigned short* __restrict__ Ybf, const int* __restrict__ off,
    const int* __restrict__ srcs, const float* __restrict__ dinv,
    const float* __restrict__ bias, float* __restrict__ O, int n)
{
    int node = blockIdx.x * 4 + (threadIdx.x >> 6);
    if (node >= n) return;
    int l  = threadIdx.x & 63;
    int q  = l >> 4;             // edge slot (0..3)
    int ch = (l & 15) * 2;       // channel pair
    int beg = off[node], end = off[node + 1];
    float a0 = 0.f, a1 = 0.f;
    int j = beg;
    for (; j + 16 <= end; j += 16) {
        #pragma unroll
        for (int k = 0; k < 4; ++k) {
            int src = srcs[j + 4 * k + q];
            ushort2 u = *(const ushort2*)&Ybf[(size_t)src * 32 + ch];
            a0 += bf2f(u.x); a1 += bf2f(u.y);
        }
    }
    for (; j + 4 <= end; j += 4) {
        int src = srcs[j + q];
        ushort2 u = *(const ushort2*)&Ybf[(size_t)src * 32 + ch];
        a0 += bf2f(u.x); a1 += bf2f(u.y);
    }
    if (q < end - j) {           // tail (0..3 edges)
        int src = srcs[j + q];
        ushort2 u = *(const ushort2*)&Ybf[(size_t)src * 32 + ch];
        a0 += bf2f(u.x); a1 += bf2f(u.y);
    }
    if (q == 0) {                // self-loop
        ushort2 u = *(const ushort2*)&Ybf[(size_t)node * 32 + ch];
        a0 += bf2f(u.x); a1 += bf2f(u.y);
    }
    a0 += __shfl_xor(a0, 16, 64);
    a1 += __shfl_xor(a1, 16, 64);
    a0 += __shfl_xor(a0, 32, 64);
    a1 += __shfl_xor(a1, 32, 64);
    if (q == 0) {
        float d = dinv[node];
        float2 o;
        o.x = fmaf(d, a0, bias[ch]);
        o.y = fmaf(d, a1, bias[ch + 1]);
        *(float2*)&O[(size_t)node * 32 + ch] = o;
    }
}

extern "C" void kernel_launch(void* const* d_in, const int* in_sizes, int n_in,
                              void* d_out, int out_size, void* d_ws, size_t ws_size,
                              hipStream_t stream) {
    const float* x  = (const float*)d_in[0];
    const int*   ei = (const int*)d_in[1];
    const float* W1 = (const float*)d_in[2];
    const float* b1 = (const float*)d_in[3];
    const float* W2 = (const float*)d_in[4];
    const float* b2 = (const float*)d_in[5];
    float* out = (float*)d_out;

    const int n = NN;
    const int E = in_sizes[1] / 2;
    const int* rowi = ei;
    const int* coli = ei + E;
    const int chunk = (((E + NBLK - 1) / NBLK) + 3) & ~3;   // multiple of 4 for int4 loads

    // workspace layout, 256 B-aligned segments
    char* p = (char*)d_ws;
    auto alloc = [&p](size_t bytes) { char* q = p; p += (bytes + 255) & ~(size_t)255; return q; };
    int*   bhist  = (int*)alloc((size_t)BH_TOT * 4);
    int*   blksum = (int*)alloc(32 * 4);
    int*   off    = (int*)alloc((size_t)(n + 1) * 4);
    float* dinv   = (float*)alloc((size_t)n * 4);
    int*   srcs   = (int*)alloc((size_t)E * 4);
    unsigned short* Ybf1 = (unsigned short*)alloc((size_t)n * 64 * 2);
    unsigned short* Ybf2 = (unsigned short*)alloc((size_t)n * 32 * 2);
    unsigned int* cbin = (unsigned int*)Ybf1;   // alias: cbin dead before Ybf1 written

    // ---- CSR build (counting sort, shared across both layers) ----
    k_hist1<<<NBLK, 256, 0, stream>>>(coli, bhist, E, chunk);
    int nbs = (BH_TOT + 1023) / 1024;   // 25
    k_scanA<<<nbs, 1024, 0, stream>>>(bhist, blksum, BH_TOT);
    k_scanC<<<(BH_TOT + 255) / 256, 256, 0, stream>>>(bhist, blksum, nbs, BH_TOT, off, E);
    k_bin2<<<NBLK, 256, 0, stream>>>(rowi, coli, bhist, cbin, E, chunk);
    k_csr<<<NFB, 1024, 0, stream>>>(cbin, bhist, off, dinv, srcs, n, E);

    // ---- layer 1 GEMM (in 64 -> hid 64, scaled, bf16) ----
    k_gemm64<<<(n + 15) / 16, 256, 0, stream>>>(x, W1, dinv, Ybf1, n);

    // ---- fused: layer-1 aggregate + relu + layer-2 GEMM (scaled, bf16) ----
    k_agg64g<<<AGG_BLKS, 256, 0, stream>>>(Ybf1, off, srcs, dinv, b1, W2, Ybf2, n);

    // ---- layer 2 aggregate -> output ----
    k_agg32<<<(n + 3) / 4, 256, 0, stream>>>(Ybf2, off, srcs, dinv, b2, out, n);
}

// Round 17
// 184.046 us; speedup vs baseline: 1.1319x; 1.1319x over previous
//
#include <hip/hip_runtime.h>
#include <type_traits>

#define NN 100000
#define FB_SH 10                 // fine bucket shift: bucket = col >> 10
#define FB_N  1024               // nodes per bucket
#define NFB   98                 // ceil(100000/1024)
#define NBLK  256                // binning blocks
#define BH_TOT (NFB * NBLK)      // 25088

// bf16 helpers (RN-even)
static __device__ __forceinline__ unsigned short f2bf(float f) {
    unsigned u = __float_as_uint(f);
    u += 0x7fffu + ((u >> 16) & 1u);
    return (unsigned short)(u >> 16);
}
static __device__ __forceinline__ float bf2f(unsigned short h) {
    return __uint_as_float(((unsigned)h) << 16);
}

// ================= CSR build: stable two-pass counting sort =================
// chunk is a multiple of 4 (host guarantees) so int4 loads are aligned.

__global__ __launch_bounds__(256) void k_hist1(const int* __restrict__ coli,
                                               int* __restrict__ bhist, int E, int chunk) {
    __shared__ int h[NFB];
    for (int i = threadIdx.x; i < NFB; i += 256) h[i] = 0;
    __syncthreads();
    int bk = blockIdx.x;
    int beg = bk * chunk, end = min(E, beg + chunk);
    for (int e = beg + threadIdx.x * 4; e < end; e += 1024) {
        if (e + 4 <= end) {
            int4 c = *(const int4*)&coli[e];
            atomicAdd(&h[c.x >> FB_SH], 1);
            atomicAdd(&h[c.y >> FB_SH], 1);
            atomicAdd(&h[c.z >> FB_SH], 1);
            atomicAdd(&h[c.w >> FB_SH], 1);
        } else {
            for (int t = e; t < end; ++t) atomicAdd(&h[coli[t] >> FB_SH], 1);
        }
    }
    __syncthreads();
    for (int i = threadIdx.x; i < NFB; i += 256)
        bhist[i * NBLK + bk] = h[i];   // bucket-major for the scan
}

__global__ __launch_bounds__(1024) void k_scanA(int* __restrict__ a,
                                                int* __restrict__ blksum, int n) {
    __shared__ int sh[1024];
    int i = blockIdx.x * 1024 + threadIdx.x;
    int v = (i < n) ? a[i] : 0;
    sh[threadIdx.x] = v;
    __syncthreads();
    #pragma unroll
    for (int d = 1; d < 1024; d <<= 1) {
        int t = (threadIdx.x >= d) ? sh[threadIdx.x - d] : 0;
        __syncthreads();
        sh[threadIdx.x] += t;
        __syncthreads();
    }
    if (i < n) a[i] = sh[threadIdx.x] - v;   // local exclusive
    if (threadIdx.x == 1023) blksum[blockIdx.x] = sh[1023];
}

// scanB fused in: each block loads the raw block sums, thread 0 scans in LDS.
__global__ __launch_bounds__(256) void k_scanC(int* __restrict__ a,
                                               const int* __restrict__ blksum,
                                               int nbs, int n,
                                               int* __restrict__ off, int E) {
    __shared__ int pre[32];
    if (threadIdx.x < 32) pre[threadIdx.x] = (threadIdx.x < nbs) ? blksum[threadIdx.x] : 0;
    __syncthreads();
    if (threadIdx.x == 0) {
        int s = 0;
        for (int b = 0; b < nbs; ++b) { int t = pre[b]; pre[b] = s; s += t; }
    }
    __syncthreads();
    int i = blockIdx.x * 256 + threadIdx.x;
    if (i < n) a[i] += pre[i >> 10];
    if (i == 0) off[NN] = E;
}

__global__ __launch_bounds__(256) void k_bin2(
    const int* __restrict__ rowi, const int* __restrict__ coli,
    const int* __restrict__ bbase, unsigned int* __restrict__ cbin, int E, int chunk)
{
    __shared__ int cur[NFB];
    int bk = blockIdx.x;
    for (int i = threadIdx.x; i < NFB; i += 256) cur[i] = bbase[i * NBLK + bk];
    __syncthreads();
    int beg = bk * chunk, end = min(E, beg + chunk);
    for (int e = beg + threadIdx.x * 4; e < end; e += 1024) {
        if (e + 4 <= end) {
            int4 c = *(const int4*)&coli[e];
            int4 r = *(const int4*)&rowi[e];
            int b0 = c.x >> FB_SH, b1 = c.y >> FB_SH, b2 = c.z >> FB_SH, b3 = c.w >> FB_SH;
            unsigned v0 = ((unsigned)r.x << FB_SH) | (unsigned)(c.x & (FB_N - 1));
            unsigned v1 = ((unsigned)r.y << FB_SH) | (unsigned)(c.y & (FB_N - 1));
            unsigned v2 = ((unsigned)r.z << FB_SH) | (unsigned)(c.z & (FB_N - 1));
            unsigned v3 = ((unsigned)r.w << FB_SH) | (unsigned)(c.w & (FB_N - 1));
            cbin[atomicAdd(&cur[b0], 1)] = v0;
            cbin[atomicAdd(&cur[b1], 1)] = v1;
            cbin[atomicAdd(&cur[b2], 1)] = v2;
            cbin[atomicAdd(&cur[b3], 1)] = v3;
        } else {
            for (int t = e; t < end; ++t) {
                int col = coli[t], row = rowi[t];
                int b = col >> FB_SH;
                unsigned val = ((unsigned)row << FB_SH) | (unsigned)(col & (FB_N - 1));
                cbin[atomicAdd(&cur[b], 1)] = val;
            }
        }
    }
}

__global__ __launch_bounds__(1024) void k_csr(
    const unsigned int* __restrict__ cbin, const int* __restrict__ bbase,
    int* __restrict__ off, float* __restrict__ dinv,
    int* __restrict__ srcs, int n, int E)
{
    __shared__ int hist[FB_N];
    __shared__ int wsum[16];
    int b = blockIdx.x;
    int beg = bbase[b * NBLK];
    int end = (b + 1 < NFB) ? bbase[(b + 1) * NBLK] : E;
    int tid = threadIdx.x;
    hist[tid] = 0;
    __syncthreads();
    // aligned sub-range for uint4 loads
    int beg4 = min((beg + 3) & ~3, end);
    int end4 = max(end & ~3, beg4);
    int nhead = beg4 - beg;          // 0..3
    int ntail = end - end4;          // 0..3
    // pass A: per-node histogram
    if (tid < nhead) atomicAdd(&hist[cbin[beg + tid] & (FB_N - 1)], 1);
    if (tid >= 4 && tid < 4 + ntail) atomicAdd(&hist[cbin[end4 + tid - 4] & (FB_N - 1)], 1);
    for (int e = beg4 + tid * 4; e < end4; e += 4096) {
        uint4 c = *(const uint4*)&cbin[e];
        atomicAdd(&hist[c.x & (FB_N - 1)], 1);
        atomicAdd(&hist[c.y & (FB_N - 1)], 1);
        atomicAdd(&hist[c.z & (FB_N - 1)], 1);
        atomicAdd(&hist[c.w & (FB_N - 1)], 1);
    }
    __syncthreads();
    int v = hist[tid];
    int lane = tid & 63;
    int wid  = tid >> 6;
    int incl = v;
    #pragma unroll
    for (int d = 1; d < 64; d <<= 1) {
        int t = __shfl_up(incl, d, 64);
        if (lane >= d) incl += t;
    }
    if (lane == 63) wsum[wid] = incl;
    __syncthreads();
    if (wid == 0) {
        int ws = (lane < 16) ? wsum[lane] : 0;
        int wincl = ws;
        #pragma unroll
        for (int d = 1; d < 16; d <<= 1) {
            int t = __shfl_up(wincl, d, 64);
            if (lane >= d) wincl += t;
        }
        if (lane < 16) wsum[lane] = wincl - ws;
    }
    __syncthreads();
    int excl = wsum[wid] + incl - v;
    int node = (b << FB_SH) + tid;
    if (node < n) {
        off[node]  = beg + excl;
        dinv[node] = rsqrtf((float)(v + 1));   // +1 self-loop
    }
    __syncthreads();
    hist[tid] = excl;   // becomes cursor
    __syncthreads();
    // pass B: place rows
    if (tid < nhead) {
        unsigned pv = cbin[beg + tid];
        srcs[beg + atomicAdd(&hist[pv & (FB_N - 1)], 1)] = (int)(pv >> FB_SH);
    }
    if (tid >= 4 && tid < 4 + ntail) {
        unsigned pv = cbin[end4 + tid - 4];
        srcs[beg + atomicAdd(&hist[pv & (FB_N - 1)], 1)] = (int)(pv >> FB_SH);
    }
    for (int e = beg4 + tid * 4; e < end4; e += 4096) {
        uint4 c = *(const uint4*)&cbin[e];
        srcs[beg + atomicAdd(&hist[c.x & (FB_N - 1)], 1)] = (int)(c.x >> FB_SH);
        srcs[beg + atomicAdd(&hist[c.y & (FB_N - 1)], 1)] = (int)(c.y >> FB_SH);
        srcs[beg + atomicAdd(&hist[c.z & (FB_N - 1)], 1)] = (int)(c.z >> FB_SH);
        srcs[beg + atomicAdd(&hist[c.w & (FB_N - 1)], 1)] = (int)(c.w >> FB_SH);
    }
}

// ================= GEMM (layer 1): Ybf1 = bf16((X @ W1) * dinv[row]) =================
__global__ __launch_bounds__(256) void k_gemm64(
    const float* __restrict__ X, const float* __restrict__ W,
    const float* __restrict__ dinv, unsigned short* __restrict__ Ybf, int n)
{
    constexpr int DOUT = 64;
    constexpr int TPR = DOUT / 4;    // 16
    constexpr int R   = 256 / TPR;   // 16
    __shared__ float sW[64 * DOUT];
    __shared__ float sX[R * 64];

    for (int i = threadIdx.x; i < 16 * DOUT; i += 256)
        *(float4*)&sW[i * 4] = *(const float4*)&W[i * 4];
    int r0 = blockIdx.x * R;
    for (int i = threadIdx.x; i < R * 16; i += 256) {
        int lr  = i >> 4;
        int c4i = (i & 15) * 4;
        int r = r0 + lr;
        float4 v = (r < n) ? *(const float4*)&X[(size_t)r * 64 + c4i]
                           : make_float4(0.f, 0.f, 0.f, 0.f);
        *(float4*)&sX[lr * 64 + c4i] = v;
    }
    __syncthreads();

    int lr  = threadIdx.x / TPR;
    int c4  = (threadIdx.x % TPR) * 4;
    int row = r0 + lr;
    const float* xr = &sX[lr * 64];
    float4 acc = make_float4(0.f, 0.f, 0.f, 0.f);
    #pragma unroll
    for (int k = 0; k < 64; ++k) {
        float xv = xr[k];
        const float* wr = &sW[k * DOUT + c4];
        acc.x = fmaf(xv, wr[0], acc.x);
        acc.y = fmaf(xv, wr[1], acc.y);
        acc.z = fmaf(xv, wr[2], acc.z);
        acc.w = fmaf(xv, wr[3], acc.w);
    }
    if (row < n) {
        float s = dinv[row];
        ushort4 o;
        o.x = f2bf(acc.x * s);
        o.y = f2bf(acc.y * s);
        o.z = f2bf(acc.z * s);
        o.w = f2bf(acc.w * s);
        *(ushort4*)&Ybf[(size_t)row * DOUT + c4] = o;
    }
}

// ======== FUSED layer-1 aggregate + layer-2 GEMM ========
// Per node (one wave): h = relu(dinv*(Y1[i]+sum Y1[src]) + b1)   (64 ch, replicated
// across the wave after shfl_xor), then Ybf2[node] = bf16(dinv[node] * (h @ W2)).
// W2 staged in LDS (8 KB); h staged per-wave in LDS (same-wave dep, no barrier).
__global__ __launch_bounds__(256) void k_agg64g(
    const unsigned short* __restrict__ Ybf, const int* __restrict__ off,
    const int* __restrict__ srcs, const float* __restrict__ dinv,
    const float* __restrict__ bias, const float* __restrict__ W2,
    unsigned short* __restrict__ Y2, int n)
{
    __shared__ float sW2[64 * 32];           // W2[k][j]
    __shared__ float sH[4][64];
    for (int i = threadIdx.x; i < 512; i += 256)
        *(float4*)&sW2[i * 4] = *(const float4*)&W2[i * 4];
    __syncthreads();

    int w    = threadIdx.x >> 6;
    int node = blockIdx.x * 4 + w;
    if (node >= n) return;
    int l  = threadIdx.x & 63;
    int h  = l >> 5;             // edge slot (0/1)
    int ch = (l & 31) * 2;       // channel pair
    int beg = off[node], end = off[node + 1];
    float a0 = 0.f, a1 = 0.f;
    int j = beg;
    for (; j + 16 <= end; j += 16) {
        #pragma unroll
        for (int k = 0; k < 8; ++k) {
            int src = srcs[j + 2 * k + h];
            ushort2 u = *(const ushort2*)&Ybf[(size_t)src * 64 + ch];
            a0 += bf2f(u.x); a1 += bf2f(u.y);
        }
    }
    for (; j + 2 <= end; j += 2) {
        int src = srcs[j + h];
        ushort2 u = *(const ushort2*)&Ybf[(size_t)src * 64 + ch];
        a0 += bf2f(u.x); a1 += bf2f(u.y);
    }
    if (h == 0) {
        if (j < end) {   // odd leftover edge
            int src = srcs[j];
            ushort2 u = *(const ushort2*)&Ybf[(size_t)src * 64 + ch];
            a0 += bf2f(u.x); a1 += bf2f(u.y);
        }
        // self-loop
        ushort2 u = *(const ushort2*)&Ybf[(size_t)node * 64 + ch];
        a0 += bf2f(u.x); a1 += bf2f(u.y);
    }
    a0 += __shfl_xor(a0, 32, 64);
    a1 += __shfl_xor(a1, 32, 64);
    // now every lane holds the full sums for channels (ch, ch+1)
    float d = dinv[node];
    if (h == 0) {
        float h0 = fmaxf(fmaf(d, a0, bias[ch]),     0.f);
        float h1 = fmaxf(fmaf(d, a1, bias[ch + 1]), 0.f);
        sH[w][ch]     = h0;
        sH[w][ch + 1] = h1;
    }
    // matvec: lane -> output col jc = l&31, k-half = l>>5 (same-wave LDS dep)
    int jc = l & 31;
    const float* hrow = &sH[w][h * 32];
    const float* wcol = &sW2[(h * 32) * 32 + jc];
    float acc2 = 0.f;
    #pragma unroll
    for (int k = 0; k < 32; ++k)
        acc2 = fmaf(hrow[k], wcol[k * 32], acc2);
    acc2 += __shfl_xor(acc2, 32, 64);
    if (h == 0)
        Y2[(size_t)node * 32 + jc] = f2bf(d * acc2);
}

// D=32: one 64-lane wave per node; lane = (edge slot q 0..3, channel pair ch).
__global__ __launch_bounds__(256) void k_agg32(
    const unsigned short* __restrict__ Ybf, const int* __restrict__ off,
    const int* __restrict__ srcs, const float* __restrict__ dinv,
    const float* __restrict__ bias, float* __restrict__ O, int n)
{
    int node = blockIdx.x * 4 + (threadIdx.x >> 6);
    if (node >= n) return;
    int l  = threadIdx.x & 63;
    int q  = l >> 4;             // edge slot (0..3)
    int ch = (l & 15) * 2;       // channel pair
    int beg = off[node], end = off[node + 1];
    float a0 = 0.f, a1 = 0.f;
    int j = beg;
    for (; j + 16 <= end; j += 16) {
        #pragma unroll
        for (int k = 0; k < 4; ++k) {
            int src = srcs[j + 4 * k + q];
            ushort2 u = *(const ushort2*)&Ybf[(size_t)src * 32 + ch];
            a0 += bf2f(u.x); a1 += bf2f(u.y);
        }
    }
    for (; j + 4 <= end; j += 4) {
        int src = srcs[j + q];
        ushort2 u = *(const ushort2*)&Ybf[(size_t)src * 32 + ch];
        a0 += bf2f(u.x); a1 += bf2f(u.y);
    }
    if (q < end - j) {           // tail (0..3 edges)
        int src = srcs[j + q];
        ushort2 u = *(const ushort2*)&Ybf[(size_t)src * 32 + ch];
        a0 += bf2f(u.x); a1 += bf2f(u.y);
    }
    if (q == 0) {                // self-loop
        ushort2 u = *(const ushort2*)&Ybf[(size_t)node * 32 + ch];
        a0 += bf2f(u.x); a1 += bf2f(u.y);
    }
    a0 += __shfl_xor(a0, 16, 64);
    a1 += __shfl_xor(a1, 16, 64);
    a0 += __shfl_xor(a0, 32, 64);
    a1 += __shfl_xor(a1, 32, 64);
    if (q == 0) {
        float d = dinv[node];
        float2 o;
        o.x = fmaf(d, a0, bias[ch]);
        o.y = fmaf(d, a1, bias[ch + 1]);
        *(float2*)&O[(size_t)node * 32 + ch] = o;
    }
}

extern "C" void kernel_launch(void* const* d_in, const int* in_sizes, int n_in,
                              void* d_out, int out_size, void* d_ws, size_t ws_size,
                              hipStream_t stream) {
    const float* x  = (const float*)d_in[0];
    const int*   ei = (const int*)d_in[1];
    const float* W1 = (const float*)d_in[2];
    const float* b1 = (const float*)d_in[3];
    const float* W2 = (const float*)d_in[4];
    const float* b2 = (const float*)d_in[5];
    float* out = (float*)d_out;

    const int n = NN;
    const int E = in_sizes[1] / 2;
    const int* rowi = ei;
    const int* coli = ei + E;
    const int chunk = (((E + NBLK - 1) / NBLK) + 3) & ~3;   // multiple of 4 for int4 loads

    // workspace layout, 256 B-aligned segments
    char* p = (char*)d_ws;
    auto alloc = [&p](size_t bytes) { char* q = p; p += (bytes + 255) & ~(size_t)255; return q; };
    int*   bhist  = (int*)alloc((size_t)BH_TOT * 4);
    int*   blksum = (int*)alloc(32 * 4);
    int*   off    = (int*)alloc((size_t)(n + 1) * 4);
    float* dinv   = (float*)alloc((size_t)n * 4);
    int*   srcs   = (int*)alloc((size_t)E * 4);
    unsigned short* Ybf1 = (unsigned short*)alloc((size_t)n * 64 * 2);
    unsigned short* Ybf2 = (unsigned short*)alloc((size_t)n * 32 * 2);
    unsigned int* cbin = (unsigned int*)Ybf1;   // alias: cbin dead before Ybf1 written

    // ---- CSR build (counting sort, shared across both layers) ----
    k_hist1<<<NBLK, 256, 0, stream>>>(coli, bhist, E, chunk);
    int nbs = (BH_TOT + 1023) / 1024;   // 25
    k_scanA<<<nbs, 1024, 0, stream>>>(bhist, blksum, BH_TOT);
    k_scanC<<<(BH_TOT + 255) / 256, 256, 0, stream>>>(bhist, blksum, nbs, BH_TOT, off, E);
    k_bin2<<<NBLK, 256, 0, stream>>>(rowi, coli, bhist, cbin, E, chunk);
    k_csr<<<NFB, 1024, 0, stream>>>(cbin, bhist, off, dinv, srcs, n, E);

    // ---- layer 1 GEMM (in 64 -> hid 64, scaled, bf16) ----
    k_gemm64<<<(n + 15) / 16, 256, 0, stream>>>(x, W1, dinv, Ybf1, n);

    // ---- fused: layer-1 aggregate + relu + layer-2 GEMM (scaled, bf16) ----
    k_agg64g<<<(n + 3) / 4, 256, 0, stream>>>(Ybf1, off, srcs, dinv, b1, W2, Ybf2, n);

    // ---- layer 2 aggregate -> output ----
    k_agg32<<<(n + 3) / 4, 256, 0, stream>>>(Ybf2, off, srcs, dinv, b2, out, n);
}